// Round 1
// baseline (617.230 us; speedup 1.0000x reference)
//
#include <hip/hip_runtime.h>
#include <math.h>

// SelfContact: v2v_min[b,j] = min_i ( geomask[i,j] ? sq[b,i]+sq[b,j]-2*dot(v[b,i],v[b,j]) : inf )
// in_contact[b,j] = v2v_min[b,j] < 0.02^2
//
// Numerics deliberately mirror the NumPy fp32 reference:
//   sq      = (x*x + y*y) + z*z            (separate mul/add, no FMA)
//   dot     = ((xi*xj) + (yi*yj)) + (zi*zj) (np.einsum sequential loop, no FMA)
//   v2v     = (sq_i + sq_j) - 2*dot         (2*dot exact)
// using __fmul_rn/__fadd_rn/__fsub_rn to block -ffp-contract fusion.

#define NV   10475
#define NB   2
#define BLK  256
#define CPB  1024                       // columns per block (4 per thread, stride 256)
#define JB   ((NV + CPB - 1) / CPB)     // 11 column tiles
#define RC   48                         // row chunks
#define CH   ((NV + RC - 1) / RC)       // 219 rows per chunk

__device__ __forceinline__ float sq_nofma(float x, float y, float z) {
    return __fadd_rn(__fadd_rn(__fmul_rn(x, x), __fmul_rn(y, y)), __fmul_rn(z, z));
}

__global__ __launch_bounds__(BLK) void sc_partial(
    const float* __restrict__ verts,   // [NB, NV, 3]
    const int*   __restrict__ gmask,   // [NV, NV] (0/1)
    float*       __restrict__ partial) // [RC, NB, NV]
{
    __shared__ float4 sv[CH * NB];     // per staged row: (x, y, z, sq) per batch

    const int tid = threadIdx.x;
    const int jb  = blockIdx.x;
    const int rc  = blockIdx.y;
    const int r0  = rc * CH;
    const int r1  = (r0 + CH < NV) ? (r0 + CH) : NV;
    const int nrows = r1 - r0;

    // ---- stage row vertices (+sq) for both batches into LDS ----
    for (int k = tid; k < nrows * NB; k += BLK) {
        int rr = k >> 1, b = k & 1;
        const float* vp = verts + ((size_t)b * NV + (r0 + rr)) * 3;
        float x = vp[0], y = vp[1], z = vp[2];
        sv[rr * NB + b] = make_float4(x, y, z, sq_nofma(x, y, z));
    }
    __syncthreads();

    // ---- my 4 columns (stride-256 so mask loads coalesce) ----
    int  cols[4];
    bool cval[4];
    float cx[NB][4], cy[NB][4], cz[NB][4], cs[NB][4];
#pragma unroll
    for (int c = 0; c < 4; ++c) {
        int col = jb * CPB + tid + c * BLK;
        cval[c] = (col < NV);
        cols[c] = cval[c] ? col : (NV - 1);
#pragma unroll
        for (int b = 0; b < NB; ++b) {
            const float* vp = verts + ((size_t)b * NV + cols[c]) * 3;
            float x = vp[0], y = vp[1], z = vp[2];
            cx[b][c] = x; cy[b][c] = y; cz[b][c] = z;
            cs[b][c] = sq_nofma(x, y, z);
        }
    }

    float mn[NB][4];
#pragma unroll
    for (int b = 0; b < NB; ++b)
#pragma unroll
        for (int c = 0; c < 4; ++c) mn[b][c] = __builtin_inff();

    // ---- main loop over rows of this chunk ----
    for (int i = r0; i < r1; ++i) {
        const int* grow = gmask + (size_t)i * NV;
        float4 a0 = sv[(i - r0) * NB + 0];
        float4 a1 = sv[(i - r0) * NB + 1];
#pragma unroll
        for (int c = 0; c < 4; ++c) {
            int  mk  = grow[cols[c]];
            bool act = cval[c] && (mk != 0);

            float d0 = __fadd_rn(__fadd_rn(__fmul_rn(a0.x, cx[0][c]),
                                           __fmul_rn(a0.y, cy[0][c])),
                                 __fmul_rn(a0.z, cz[0][c]));
            float v0 = __fsub_rn(__fadd_rn(a0.w, cs[0][c]), 2.0f * d0);
            mn[0][c] = fminf(mn[0][c], act ? v0 : __builtin_inff());

            float d1 = __fadd_rn(__fadd_rn(__fmul_rn(a1.x, cx[1][c]),
                                           __fmul_rn(a1.y, cy[1][c])),
                                 __fmul_rn(a1.z, cz[1][c]));
            float v1 = __fsub_rn(__fadd_rn(a1.w, cs[1][c]), 2.0f * d1);
            mn[1][c] = fminf(mn[1][c], act ? v1 : __builtin_inff());
        }
    }

    // ---- write partial mins ----
#pragma unroll
    for (int c = 0; c < 4; ++c) {
        if (cval[c]) {
            size_t base = (size_t)rc * (NB * NV);
            partial[base + 0 * NV + cols[c]] = mn[0][c];
            partial[base + 1 * NV + cols[c]] = mn[1][c];
        }
    }
}

__global__ __launch_bounds__(BLK) void sc_reduce(
    const float* __restrict__ partial,  // [RC, NB, NV]
    float*       __restrict__ out)      // [NB*NV] mins then [NB*NV] contact
{
    int idx = blockIdx.x * BLK + threadIdx.x;
    if (idx >= NB * NV) return;
    float m = __builtin_inff();
#pragma unroll 4
    for (int r = 0; r < RC; ++r)
        m = fminf(m, partial[(size_t)r * (NB * NV) + idx]);
    out[idx] = m;
    out[NB * NV + idx] = ((double)m < 0.02 * 0.02) ? 1.0f : 0.0f;
}

extern "C" void kernel_launch(void* const* d_in, const int* in_sizes, int n_in,
                              void* d_out, int out_size, void* d_ws, size_t ws_size,
                              hipStream_t stream) {
    const float* verts = (const float*)d_in[0];
    const int*   gmask = (const int*)d_in[1];
    float* out     = (float*)d_out;
    float* partial = (float*)d_ws;    // needs RC*NB*NV*4 = ~4.0 MB

    dim3 g1(JB, RC);
    sc_partial<<<g1, dim3(BLK), 0, stream>>>(verts, gmask, partial);

    int nred = (NB * NV + BLK - 1) / BLK;
    sc_reduce<<<nred, dim3(BLK), 0, stream>>>(partial, out);
}

// Round 2
// 609.865 us; speedup vs baseline: 1.0121x; 1.0121x over previous
//
#include <hip/hip_runtime.h>
#include <math.h>

// SelfContact: v2v_min[b,j] = min_i ( geomask[i,j] ? sq[b,i]+sq[b,j]-2*dot(v[b,i],v[b,j]) : inf )
// in_contact[b,j] = v2v_min[b,j] < 0.02^2
//
// Numerics mirror the NumPy fp32 reference: separate mul/add (no FMA) via
// __fmul_rn/__fadd_rn/__fsub_rn so -ffp-contract can't fuse.
//
// R1: latency-bound at 0.7 TB/s (528 blocks = 2/CU, no MLP in row loop).
// R2: RC 48->128 (1408 blocks ~5.5/CU) + 4-row unroll with 16 mask dword
//     loads batched ahead of the dependent compute.

#define NV   10475
#define NB   2
#define BLK  256
#define CPB  1024                       // columns per block (4 per thread, stride 256)
#define JB   ((NV + CPB - 1) / CPB)     // 11 column tiles
#define RC   128                        // row chunks
#define CH   ((NV + RC - 1) / RC)       // 82 rows per chunk
#define RU   4                          // row unroll

__device__ __forceinline__ float sq_nofma(float x, float y, float z) {
    return __fadd_rn(__fadd_rn(__fmul_rn(x, x), __fmul_rn(y, y)), __fmul_rn(z, z));
}

__global__ __launch_bounds__(BLK) void sc_partial(
    const float* __restrict__ verts,   // [NB, NV, 3]
    const int*   __restrict__ gmask,   // [NV, NV] (0/1)
    float*       __restrict__ partial) // [RC, NB, NV]
{
    __shared__ float4 sv[CH * NB];     // per staged row: (x, y, z, sq) per batch

    const int tid = threadIdx.x;
    const int jb  = blockIdx.x;
    const int rc  = blockIdx.y;
    const int r0  = rc * CH;
    const int r1  = (r0 + CH < NV) ? (r0 + CH) : NV;
    const int nrows = r1 - r0;

    // ---- stage row vertices (+sq) for both batches into LDS ----
    for (int k = tid; k < nrows * NB; k += BLK) {
        int rr = k >> 1, b = k & 1;
        const float* vp = verts + ((size_t)b * NV + (r0 + rr)) * 3;
        float x = vp[0], y = vp[1], z = vp[2];
        sv[rr * NB + b] = make_float4(x, y, z, sq_nofma(x, y, z));
    }
    __syncthreads();

    // ---- my 4 columns (stride-256 so each mask load is wave-coalesced) ----
    int  cols[4];
    bool cval[4];
    float cx[NB][4], cy[NB][4], cz[NB][4], cs[NB][4];
#pragma unroll
    for (int c = 0; c < 4; ++c) {
        int col = jb * CPB + tid + c * BLK;
        cval[c] = (col < NV);
        cols[c] = cval[c] ? col : (NV - 1);
#pragma unroll
        for (int b = 0; b < NB; ++b) {
            const float* vp = verts + ((size_t)b * NV + cols[c]) * 3;
            float x = vp[0], y = vp[1], z = vp[2];
            cx[b][c] = x; cy[b][c] = y; cz[b][c] = z;
            cs[b][c] = sq_nofma(x, y, z);
        }
    }

    float mn[NB][4];
#pragma unroll
    for (int b = 0; b < NB; ++b)
#pragma unroll
        for (int c = 0; c < 4; ++c) mn[b][c] = __builtin_inff();

    // ---- main loop: 4 rows per step, all 16 mask loads batched first ----
    int i = r0;
    for (; i + RU <= r1; i += RU) {
        int mk[RU][4];
#pragma unroll
        for (int r = 0; r < RU; ++r) {
            const int* grow = gmask + (size_t)(i + r) * NV;
#pragma unroll
            for (int c = 0; c < 4; ++c) mk[r][c] = grow[cols[c]];
        }
#pragma unroll
        for (int r = 0; r < RU; ++r) {
            float4 a0 = sv[(i - r0 + r) * NB + 0];
            float4 a1 = sv[(i - r0 + r) * NB + 1];
#pragma unroll
            for (int c = 0; c < 4; ++c) {
                bool act = cval[c] && (mk[r][c] != 0);

                float d0 = __fadd_rn(__fadd_rn(__fmul_rn(a0.x, cx[0][c]),
                                               __fmul_rn(a0.y, cy[0][c])),
                                     __fmul_rn(a0.z, cz[0][c]));
                float v0 = __fsub_rn(__fadd_rn(a0.w, cs[0][c]), 2.0f * d0);
                mn[0][c] = fminf(mn[0][c], act ? v0 : __builtin_inff());

                float d1 = __fadd_rn(__fadd_rn(__fmul_rn(a1.x, cx[1][c]),
                                               __fmul_rn(a1.y, cy[1][c])),
                                     __fmul_rn(a1.z, cz[1][c]));
                float v1 = __fsub_rn(__fadd_rn(a1.w, cs[1][c]), 2.0f * d1);
                mn[1][c] = fminf(mn[1][c], act ? v1 : __builtin_inff());
            }
        }
    }
    // tail rows
    for (; i < r1; ++i) {
        const int* grow = gmask + (size_t)i * NV;
        float4 a0 = sv[(i - r0) * NB + 0];
        float4 a1 = sv[(i - r0) * NB + 1];
#pragma unroll
        for (int c = 0; c < 4; ++c) {
            bool act = cval[c] && (grow[cols[c]] != 0);

            float d0 = __fadd_rn(__fadd_rn(__fmul_rn(a0.x, cx[0][c]),
                                           __fmul_rn(a0.y, cy[0][c])),
                                 __fmul_rn(a0.z, cz[0][c]));
            float v0 = __fsub_rn(__fadd_rn(a0.w, cs[0][c]), 2.0f * d0);
            mn[0][c] = fminf(mn[0][c], act ? v0 : __builtin_inff());

            float d1 = __fadd_rn(__fadd_rn(__fmul_rn(a1.x, cx[1][c]),
                                           __fmul_rn(a1.y, cy[1][c])),
                                 __fmul_rn(a1.z, cz[1][c]));
            float v1 = __fsub_rn(__fadd_rn(a1.w, cs[1][c]), 2.0f * d1);
            mn[1][c] = fminf(mn[1][c], act ? v1 : __builtin_inff());
        }
    }

    // ---- write partial mins ----
#pragma unroll
    for (int c = 0; c < 4; ++c) {
        if (cval[c]) {
            size_t base = (size_t)rc * (NB * NV);
            partial[base + 0 * NV + cols[c]] = mn[0][c];
            partial[base + 1 * NV + cols[c]] = mn[1][c];
        }
    }
}

__global__ __launch_bounds__(BLK) void sc_reduce(
    const float* __restrict__ partial,  // [RC, NB, NV]
    float*       __restrict__ out)      // [NB*NV] mins then [NB*NV] contact
{
    int idx = blockIdx.x * BLK + threadIdx.x;
    if (idx >= NB * NV) return;
    float m = __builtin_inff();
#pragma unroll 8
    for (int r = 0; r < RC; ++r)
        m = fminf(m, partial[(size_t)r * (NB * NV) + idx]);
    out[idx] = m;
    out[NB * NV + idx] = ((double)m < 0.02 * 0.02) ? 1.0f : 0.0f;
}

extern "C" void kernel_launch(void* const* d_in, const int* in_sizes, int n_in,
                              void* d_out, int out_size, void* d_ws, size_t ws_size,
                              hipStream_t stream) {
    const float* verts = (const float*)d_in[0];
    const int*   gmask = (const int*)d_in[1];
    float* out     = (float*)d_out;
    float* partial = (float*)d_ws;    // needs RC*NB*NV*4 = ~10.7 MB

    dim3 g1(JB, RC);
    sc_partial<<<g1, dim3(BLK), 0, stream>>>(verts, gmask, partial);

    int nred = (NB * NV + BLK - 1) / BLK;
    sc_reduce<<<nred, dim3(BLK), 0, stream>>>(partial, out);
}

// Round 3
// 591.444 us; speedup vs baseline: 1.0436x; 1.0311x over previous
//
#include <hip/hip_runtime.h>
#include <math.h>

// SelfContact: v2v_min[b,j] = min_i ( geomask[i,j] ? sq[b,i]+sq[b,j]-2*dot(v[b,i],v[b,j]) : inf )
// in_contact[b,j] = v2v_min[b,j] < 0.02^2
//
// Numerics mirror the NumPy fp32 reference exactly: separate mul/add (no FMA)
// via __fmul_rn/__fadd_rn/__fsub_rn. The 2*dot is folded into pre-doubled
// column coords (scaling by 2 commutes with round-to-nearest — bitwise equal).
//
// R3: exploit symmetry. geomask is symmetric (setup symmetrizes) and v2v is
// bitwise-symmetric in (i,j) under this formulation, so each pair (i<=j) is
// computed once: updates col-min[j] (registers) AND row-min[i] (DPP wave
// reduction on the VALU pipe, lane 63 -> LDS). Only upper-triangle tiles
// launch -> mask reads 439 MB -> ~225 MB. Duplicate pairs near the diagonal
// are harmless (min idempotent, bitwise-equal values). No atomics: partial
// slots have unique writers; the reduce kernel enumerates exactly the valid
// slots, so 0xAA-poisoned unwritten slots are never read.

#define NV   10475
#define NB   2
#define BLK  256
#define CPB  1024                       // columns per block (4 per thread, stride 256)
#define JB   ((NV + CPB - 1) / CPB)     // 11 column tiles
#define CH   48                         // rows per chunk
#define RC   ((NV + CH - 1) / CH)       // 219 row chunks
#define RU   4                          // row unroll

__device__ __forceinline__ float sq_nofma(float x, float y, float z) {
    return __fadd_rn(__fadd_rn(__fmul_rn(x, x), __fmul_rn(y, y)), __fmul_rn(z, z));
}

template <int CTRL>
__device__ __forceinline__ float dppmin(float v) {
    int s = __builtin_amdgcn_update_dpp(__float_as_int(v), __float_as_int(v),
                                        CTRL, 0xF, 0xF, false);
    return fminf(v, __int_as_float(s));
}

// Full-wave (64-lane) min; result valid in lane 63. All lanes must be active.
__device__ __forceinline__ float wave_min_to_lane63(float v) {
    v = dppmin<0x111>(v);  // row_shr:1
    v = dppmin<0x112>(v);  // row_shr:2
    v = dppmin<0x114>(v);  // row_shr:4
    v = dppmin<0x118>(v);  // row_shr:8  -> lane 15 of each row16 = row min
    v = dppmin<0x142>(v);  // row_bcast:15
    v = dppmin<0x143>(v);  // row_bcast:31 -> lane 63 = wave min
    return v;
}

__global__ __launch_bounds__(BLK) void sc_partial(
    const float* __restrict__ verts,    // [NB, NV, 3]
    const int*   __restrict__ gmask,    // [NV, NV]
    float*       __restrict__ colpart,  // [RC, NB, NV]
    float*       __restrict__ rowpart)  // [JB, NB, NV]
{
    __shared__ float4 sv[CH * NB];       // staged row verts: (x,y,z,sq) per batch
    __shared__ float  rmin[CH][4][NB];   // per-row per-wave row-min

    const int tid  = threadIdx.x;
    const int jb   = blockIdx.x;
    const int rcb  = blockIdx.y;
    const int j0   = jb * CPB;
    const int jmax = (j0 + CPB - 1 < NV - 1) ? (j0 + CPB - 1) : (NV - 1);
    const int r0   = rcb * CH;
    if (r0 > jmax) return;               // strictly-below-diagonal tile: skip
    const int r1    = ((r0 + CH < jmax + 1) ? (r0 + CH) : (jmax + 1));
    const int nrows = r1 - r0;
    const int wv    = tid >> 6;

    // ---- stage row vertices (+sq) for both batches into LDS ----
    for (int k = tid; k < nrows * NB; k += BLK) {
        int rr = k >> 1, b = k & 1;
        const float* vp = verts + ((size_t)b * NV + (r0 + rr)) * 3;
        float x = vp[0], y = vp[1], z = vp[2];
        sv[rr * NB + b] = make_float4(x, y, z, sq_nofma(x, y, z));
    }
    __syncthreads();

    // ---- my 4 columns (stride-256 so each mask load is wave-coalesced) ----
    int  cols[4];
    bool cval[4];
    float cx2[NB][4], cy2[NB][4], cz2[NB][4], cs[NB][4];  // coords pre-doubled
#pragma unroll
    for (int c = 0; c < 4; ++c) {
        int col = j0 + tid + c * BLK;
        cval[c] = (col < NV);
        cols[c] = cval[c] ? col : (NV - 1);
#pragma unroll
        for (int b = 0; b < NB; ++b) {
            const float* vp = verts + ((size_t)b * NV + cols[c]) * 3;
            float x = vp[0], y = vp[1], z = vp[2];
            cx2[b][c] = __fmul_rn(2.0f, x);
            cy2[b][c] = __fmul_rn(2.0f, y);
            cz2[b][c] = __fmul_rn(2.0f, z);
            cs[b][c]  = sq_nofma(x, y, z);
        }
    }

    float mn[NB][4];
#pragma unroll
    for (int b = 0; b < NB; ++b)
#pragma unroll
        for (int c = 0; c < 4; ++c) mn[b][c] = __builtin_inff();

#define ROW_BODY(ROWIDX, MK0, MK1, MK2, MK3)                                   \
    {                                                                          \
        int rr = (ROWIDX);                                                     \
        float4 a0 = sv[rr * NB + 0];                                           \
        float4 a1 = sv[rr * NB + 1];                                           \
        float rf0 = __builtin_inff(), rf1 = __builtin_inff();                  \
        int mks[4] = {MK0, MK1, MK2, MK3};                                     \
        _Pragma("unroll")                                                      \
        for (int c = 0; c < 4; ++c) {                                          \
            bool act = cval[c] && (mks[c] != 0);                               \
            float d0 = __fadd_rn(__fadd_rn(__fmul_rn(a0.x, cx2[0][c]),         \
                                           __fmul_rn(a0.y, cy2[0][c])),        \
                                 __fmul_rn(a0.z, cz2[0][c]));                  \
            float v0 = __fsub_rn(__fadd_rn(a0.w, cs[0][c]), d0);               \
            float t0 = act ? v0 : __builtin_inff();                            \
            mn[0][c] = fminf(mn[0][c], t0);                                    \
            rf0      = fminf(rf0, t0);                                         \
            float d1 = __fadd_rn(__fadd_rn(__fmul_rn(a1.x, cx2[1][c]),         \
                                           __fmul_rn(a1.y, cy2[1][c])),        \
                                 __fmul_rn(a1.z, cz2[1][c]));                  \
            float v1 = __fsub_rn(__fadd_rn(a1.w, cs[1][c]), d1);               \
            float t1 = act ? v1 : __builtin_inff();                            \
            mn[1][c] = fminf(mn[1][c], t1);                                    \
            rf1      = fminf(rf1, t1);                                         \
        }                                                                      \
        rf0 = wave_min_to_lane63(rf0);                                         \
        rf1 = wave_min_to_lane63(rf1);                                         \
        if ((tid & 63) == 63) {                                                \
            rmin[rr][wv][0] = rf0;                                             \
            rmin[rr][wv][1] = rf1;                                             \
        }                                                                      \
    }

    // ---- main loop: RU rows per step, mask loads batched ahead of compute ----
    int i = r0;
    for (; i + RU <= r1; i += RU) {
        int mk[RU][4];
#pragma unroll
        for (int r = 0; r < RU; ++r) {
            const int* grow = gmask + (size_t)(i + r) * NV;
#pragma unroll
            for (int c = 0; c < 4; ++c) mk[r][c] = grow[cols[c]];
        }
#pragma unroll
        for (int r = 0; r < RU; ++r)
            ROW_BODY(i - r0 + r, mk[r][0], mk[r][1], mk[r][2], mk[r][3]);
    }
    for (; i < r1; ++i) {
        const int* grow = gmask + (size_t)i * NV;
        int m0 = grow[cols[0]], m1 = grow[cols[1]];
        int m2 = grow[cols[2]], m3 = grow[cols[3]];
        ROW_BODY(i - r0, m0, m1, m2, m3);
    }
#undef ROW_BODY

    __syncthreads();

    // ---- write row-min partials (unique writer: block (jb, chunk(i))) ----
    for (int k = tid; k < nrows * NB; k += BLK) {
        int rr = k >> 1, b = k & 1;
        float m = fminf(fminf(rmin[rr][0][b], rmin[rr][1][b]),
                        fminf(rmin[rr][2][b], rmin[rr][3][b]));
        rowpart[((size_t)jb * NB + b) * NV + (r0 + rr)] = m;
    }

    // ---- write col-min partials (unique writer: block (tile(j), rcb)) ----
#pragma unroll
    for (int c = 0; c < 4; ++c) {
        if (cval[c]) {
            colpart[((size_t)rcb * NB + 0) * NV + cols[c]] = mn[0][c];
            colpart[((size_t)rcb * NB + 1) * NV + cols[c]] = mn[1][c];
        }
    }
}

__global__ __launch_bounds__(BLK) void sc_reduce(
    const float* __restrict__ colpart,  // [RC, NB, NV]
    const float* __restrict__ rowpart,  // [JB, NB, NV]
    float*       __restrict__ out)      // [NB*NV] mins then [NB*NV] contact
{
    int idx = blockIdx.x * BLK + threadIdx.x;
    if (idx >= NB * NV) return;
    int b = idx / NV, j = idx - b * NV;

    int jb    = j / CPB;
    int jmax  = ((jb + 1) * CPB - 1 < NV - 1) ? ((jb + 1) * CPB - 1) : (NV - 1);
    int rcmax = jmax / CH;   // exactly the chunks whose block (jb, rcb) ran

    float m = __builtin_inff();
    for (int rcb = 0; rcb <= rcmax; ++rcb)
        m = fminf(m, colpart[((size_t)rcb * NB + b) * NV + j]);
#pragma unroll
    for (int jb2 = 0; jb2 < JB; ++jb2)   // rowpart[jb2][b][j] valid iff jb2 >= jb
        if (jb2 >= jb)
            m = fminf(m, rowpart[((size_t)jb2 * NB + b) * NV + j]);

    out[idx] = m;
    out[NB * NV + idx] = ((double)m < 0.02 * 0.02) ? 1.0f : 0.0f;
}

extern "C" void kernel_launch(void* const* d_in, const int* in_sizes, int n_in,
                              void* d_out, int out_size, void* d_ws, size_t ws_size,
                              hipStream_t stream) {
    const float* verts = (const float*)d_in[0];
    const int*   gmask = (const int*)d_in[1];
    float* out     = (float*)d_out;
    float* colpart = (float*)d_ws;                          // RC*NB*NV*4  ~18.4 MB
    float* rowpart = colpart + (size_t)RC * NB * NV;        // JB*NB*NV*4  ~0.9 MB

    dim3 g1(JB, RC);   // lower-triangle tiles early-exit
    sc_partial<<<g1, dim3(BLK), 0, stream>>>(verts, gmask, colpart, rowpart);

    int nred = (NB * NV + BLK - 1) / BLK;
    sc_reduce<<<nred, dim3(BLK), 0, stream>>>(colpart, rowpart, out);
}